// Round 2
// baseline (450.099 us; speedup 1.0000x reference)
//
#include <hip/hip_runtime.h>
#include <math.h>

// Problem: B=4, S=8192, H=2048, K=4, fp32. Causal depthwise conv + SiLU.
#define CB 4
#define CS 8192
#define CH 2048
#define CH4 (CH / 4)          // 512 float4 groups per row
#define TT 32                 // timesteps per block (halo 3/32 = 9.4%)
#define TSTRIPS (CS / TT)     // 256

typedef float f4 __attribute__((ext_vector_type(4)));

__device__ __forceinline__ f4 silu4(f4 v) {
    f4 r;
    r.x = v.x * __builtin_amdgcn_rcpf(1.0f + __expf(-v.x));
    r.y = v.y * __builtin_amdgcn_rcpf(1.0f + __expf(-v.y));
    r.z = v.z * __builtin_amdgcn_rcpf(1.0f + __expf(-v.z));
    r.w = v.w * __builtin_amdgcn_rcpf(1.0f + __expf(-v.w));
    return r;
}

__device__ __forceinline__ f4 conv4(f4 w0, f4 w1, f4 w2, f4 w3,
                                    f4 m3, f4 m2, f4 m1, f4 c) {
    f4 o;
    o.x = w0.x * m3.x + w0.y * m2.x + w0.z * m1.x + w0.w * c.x;
    o.y = w1.x * m3.y + w1.y * m2.y + w1.z * m1.y + w1.w * c.y;
    o.z = w2.x * m3.z + w2.y * m2.z + w2.z * m1.z + w2.w * c.z;
    o.w = w3.x * m3.w + w3.y * m2.w + w3.z * m1.w + w3.w * c.w;
    return o;
}

// One block = full 8KB row width (256 threads x 2 float4 columns), TT rows.
// Explicit distance-4 prefetch pipeline: slots A0..A3/B0..B3 hold rows
// t..t+3; each sub-step consumes slot j, then reloads it with row t+4.
// Steady state ~8 outstanding global loads per wave (vs ~1-2 before).
__global__ __launch_bounds__(256) void dwconv_silu_kernel(
        const float* __restrict__ x,
        const float* __restrict__ w,
        float* __restrict__ y) {
    const int thr = threadIdx.x;
    const int blk = blockIdx.x;
    const int b   = blk >> 8;                    // / TSTRIPS
    const int t0  = (blk & (TSTRIPS - 1)) * TT;
    const int h4a = thr;                         // 0..255
    const int h4b = thr + 256;                   // 256..511

    const size_t base = (size_t)b * CS * CH4 + (size_t)t0 * CH4;
    const f4* __restrict__ xa  = (const f4*)x + base + h4a;
    const f4* __restrict__ xbp = (const f4*)x + base + h4b;
    f4* __restrict__ ya = (f4*)y + base + h4a;
    f4* __restrict__ yb = (f4*)y + base + h4b;

    // Weight taps: wv[h] = 4 taps of channel h. Output elem c of group h4
    // uses channel 4*h4+c.
    const f4* __restrict__ wv = (const f4*)w;
    const f4 wa0 = wv[h4a * 4 + 0], wa1 = wv[h4a * 4 + 1];
    const f4 wa2 = wv[h4a * 4 + 2], wa3 = wv[h4a * 4 + 3];
    const f4 wb0 = wv[h4b * 4 + 0], wb1 = wv[h4b * 4 + 1];
    const f4 wb2 = wv[h4b * 4 + 2], wb3 = wv[h4b * 4 + 3];

    // Sliding window (rows t-3..t-1), zero-padded at sequence start.
    f4 za3 = 0.f, za2 = 0.f, za1 = 0.f;
    f4 zb3 = 0.f, zb2 = 0.f, zb1 = 0.f;
    if (t0 != 0) {   // wave-uniform branch (t0 uniform per block)
        za3 = xa[-3 * CH4];  za2 = xa[-2 * CH4];  za1 = xa[-1 * CH4];
        zb3 = xbp[-3 * CH4]; zb2 = xbp[-2 * CH4]; zb1 = xbp[-1 * CH4];
    }

    // Prime prefetch slots with rows t0..t0+3.
    f4 A0 = xa[0 * CH4],  A1 = xa[1 * CH4],  A2 = xa[2 * CH4],  A3 = xa[3 * CH4];
    f4 B0 = xbp[0 * CH4], B1 = xbp[1 * CH4], B2 = xbp[2 * CH4], B3 = xbp[3 * CH4];

    const f4* __restrict__ xap = xa + 4 * CH4;   // next row to prefetch (a)
    const f4* __restrict__ xbq = xbp + 4 * CH4;  // next row to prefetch (b)

#define STEP_PF(Aj, Bj)                                                   \
    {                                                                     \
        f4 oa = conv4(wa0, wa1, wa2, wa3, za3, za2, za1, Aj);             \
        f4 ob = conv4(wb0, wb1, wb2, wb3, zb3, zb2, zb1, Bj);             \
        __builtin_nontemporal_store(silu4(oa), ya);                       \
        __builtin_nontemporal_store(silu4(ob), yb);                       \
        za3 = za2; za2 = za1; za1 = Aj;                                   \
        zb3 = zb2; zb2 = zb1; zb1 = Bj;                                   \
        Aj = *xap; Bj = *xbq;                                             \
        xap += CH4; xbq += CH4; ya += CH4; yb += CH4;                     \
    }

#define STEP_NOPF(Aj, Bj)                                                 \
    {                                                                     \
        f4 oa = conv4(wa0, wa1, wa2, wa3, za3, za2, za1, Aj);             \
        f4 ob = conv4(wb0, wb1, wb2, wb3, zb3, zb2, zb1, Bj);             \
        __builtin_nontemporal_store(silu4(oa), ya);                       \
        __builtin_nontemporal_store(silu4(ob), yb);                       \
        za3 = za2; za2 = za1; za1 = Aj;                                   \
        zb3 = zb2; zb2 = zb1; zb1 = Bj;                                   \
        ya += CH4; yb += CH4;                                             \
    }

    // Main pipeline: 7 bodies x 4 rows = rows 0..27; prefetch reaches row 31
    // (never out of strip, so no OOB guards needed).
    #pragma unroll 1
    for (int it = 0; it < TT / 4 - 1; ++it) {
        STEP_PF(A0, B0)
        STEP_PF(A1, B1)
        STEP_PF(A2, B2)
        STEP_PF(A3, B3)
    }
    // Epilogue: rows 28..31, no prefetch.
    STEP_NOPF(A0, B0)
    STEP_NOPF(A1, B1)
    STEP_NOPF(A2, B2)
    STEP_NOPF(A3, B3)

#undef STEP_PF
#undef STEP_NOPF
}

extern "C" void kernel_launch(void* const* d_in, const int* in_sizes, int n_in,
                              void* d_out, int out_size, void* d_ws, size_t ws_size,
                              hipStream_t stream) {
    const float* x = (const float*)d_in[0];   // (B, S, H) fp32
    const float* w = (const float*)d_in[1];   // (H, K) fp32
    float* y = (float*)d_out;                 // (B, S, H) fp32

    const int blocks = CB * TSTRIPS;          // 4 * 256 = 1024
    dwconv_silu_kernel<<<blocks, 256, 0, stream>>>(x, w, y);
}

// Round 3
// 428.284 us; speedup vs baseline: 1.0509x; 1.0509x over previous
//
#include <hip/hip_runtime.h>
#include <math.h>

// Problem: B=4, S=8192, H=2048, K=4, fp32. Causal depthwise conv + SiLU.
#define CB 4
#define CS 8192
#define CH 2048
#define CH4 (CH / 4)          // 512 float4 groups per row
#define TT 64                 // timesteps per thread (halo 3/64 = 4.7%)
#define TSTRIPS (CS / TT)     // 128

typedef float f4 __attribute__((ext_vector_type(4)));

__device__ __forceinline__ f4 silu4(f4 v) {
    f4 r;
    r.x = v.x * __builtin_amdgcn_rcpf(1.0f + __expf(-v.x));
    r.y = v.y * __builtin_amdgcn_rcpf(1.0f + __expf(-v.y));
    r.z = v.z * __builtin_amdgcn_rcpf(1.0f + __expf(-v.z));
    r.w = v.w * __builtin_amdgcn_rcpf(1.0f + __expf(-v.w));
    return r;
}

__device__ __forceinline__ f4 conv4(f4 w0, f4 w1, f4 w2, f4 w3,
                                    f4 m3, f4 m2, f4 m1, f4 c) {
    f4 o;
    o.x = w0.x * m3.x + w0.y * m2.x + w0.z * m1.x + w0.w * c.x;
    o.y = w1.x * m3.y + w1.y * m2.y + w1.z * m1.y + w1.w * c.y;
    o.z = w2.x * m3.z + w2.y * m2.z + w2.z * m1.z + w2.w * c.z;
    o.w = w3.x * m3.w + w3.y * m2.w + w3.z * m1.w + w3.w * c.w;
    return o;
}

// Software pipeline, 8-row bodies, register double buffer R/Q.
// Each body: [issue 8 NT loads for the NEXT body] [sched_barrier(0) pins
// them above the compute below] [compute+store 8 rows of current body].
// Loads always precede the stores issued after them, so in-order vmcnt
// retirement never makes a load-wait drain a store.
__global__ __launch_bounds__(256, 4) void dwconv_silu_kernel(
        const float* __restrict__ x,
        const float* __restrict__ w,
        float* __restrict__ y) {
    const int tid = blockIdx.x * 256 + threadIdx.x;
    const int h4 = tid & (CH4 - 1);          // consecutive lanes -> coalesced float4 in H
    const int strip = tid >> 9;              // tid / 512
    const int b = strip >> 7;                // / TSTRIPS
    const int t0 = (strip & (TSTRIPS - 1)) * TT;

    const f4* __restrict__ xp = (const f4*)x + (size_t)b * CS * CH4 + h4 + (size_t)t0 * CH4;
    f4* __restrict__ yp = (f4*)y + (size_t)b * CS * CH4 + h4 + (size_t)t0 * CH4;

    // Weight taps for channels 4*h4 .. 4*h4+3.
    const f4* __restrict__ wv = (const f4*)w + (size_t)h4 * 4;
    const f4 w0 = wv[0], w1 = wv[1], w2 = wv[2], w3 = wv[3];

    // Sliding window rows t0-3..t0-1 (zero-padded at sequence start; t0 is
    // uniform per block so the branch is wave-uniform).
    f4 z3 = 0.f, z2 = 0.f, z1 = 0.f;
    if (t0 != 0) {
        z3 = xp[-3 * CH4];
        z2 = xp[-2 * CH4];
        z1 = xp[-1 * CH4];
    }

    f4 r0, r1, r2, r3, r4, r5, r6, r7;
    f4 q0, q1, q2, q3, q4, q5, q6, q7;

#define LOAD8(a0, a1, a2, a3, a4, a5, a6, a7)                              \
    a0 = __builtin_nontemporal_load(xp + 0 * CH4);                         \
    a1 = __builtin_nontemporal_load(xp + 1 * CH4);                         \
    a2 = __builtin_nontemporal_load(xp + 2 * CH4);                         \
    a3 = __builtin_nontemporal_load(xp + 3 * CH4);                         \
    a4 = __builtin_nontemporal_load(xp + 4 * CH4);                         \
    a5 = __builtin_nontemporal_load(xp + 5 * CH4);                         \
    a6 = __builtin_nontemporal_load(xp + 6 * CH4);                         \
    a7 = __builtin_nontemporal_load(xp + 7 * CH4);                         \
    xp += 8 * CH4;                                                         \
    __builtin_amdgcn_sched_barrier(0);

#define ROW(c, J)                                                          \
    {                                                                      \
        f4 o = conv4(w0, w1, w2, w3, z3, z2, z1, c);                       \
        yp[(J) * CH4] = silu4(o);                                          \
        z3 = z2; z2 = z1; z1 = c;                                          \
    }

#define COMP8(a0, a1, a2, a3, a4, a5, a6, a7)                              \
    ROW(a0, 0) ROW(a1, 1) ROW(a2, 2) ROW(a3, 3)                            \
    ROW(a4, 4) ROW(a5, 5) ROW(a6, 6) ROW(a7, 7)                            \
    yp += 8 * CH4;

    // Prologue: rows t0..t0+7 into R.
    LOAD8(r0, r1, r2, r3, r4, r5, r6, r7)

    // 3 x [LQ, CR, LR, CQ] covers rows 0..47 with constant distance-8 prefetch.
    #pragma unroll 1
    for (int it = 0; it < 3; ++it) {
        LOAD8(q0, q1, q2, q3, q4, q5, q6, q7)   // rows +8..+15
        COMP8(r0, r1, r2, r3, r4, r5, r6, r7)   // rows +0..+7
        LOAD8(r0, r1, r2, r3, r4, r5, r6, r7)   // rows +16..+23
        COMP8(q0, q1, q2, q3, q4, q5, q6, q7)   // rows +8..+15
    }
    // Epilogue: rows 48..63.
    LOAD8(q0, q1, q2, q3, q4, q5, q6, q7)       // rows 56..63
    COMP8(r0, r1, r2, r3, r4, r5, r6, r7)       // rows 48..55
    COMP8(q0, q1, q2, q3, q4, q5, q6, q7)       // rows 56..63

#undef LOAD8
#undef ROW
#undef COMP8
}

extern "C" void kernel_launch(void* const* d_in, const int* in_sizes, int n_in,
                              void* d_out, int out_size, void* d_ws, size_t ws_size,
                              hipStream_t stream) {
    const float* x = (const float*)d_in[0];   // (B, S, H) fp32
    const float* w = (const float*)d_in[1];   // (H, K) fp32
    float* y = (float*)d_out;                 // (B, S, H) fp32

    const int total_threads = CB * TSTRIPS * CH4;    // 4 * 128 * 512 = 262144
    dwconv_silu_kernel<<<total_threads / 256, 256, 0, stream>>>(x, w, y);
}